// Round 1
// baseline (281.507 us; speedup 1.0000x reference)
//
#include <hip/hip_runtime.h>
#include <hip/hip_bf16.h>

#define HIDDEN 64
#define BATCH 2048
#define SFULL 1024
#define SM1 1023
#define LN_CLAMP -23.025850929940457f  // ln(1e-10)

// ---------------- Kernel 1: compute z[s'*BATCH + b] ----------------
// grid (BATCH/256, SM1), block 256. Each thread: full MLP for one (b, s).
__global__ __launch_bounds__(256) void mlp_z_kernel(
    const float* __restrict__ ys,    // (B, S, 2)
    const float* __restrict__ W1,    // (3, 64)
    const float* __restrict__ b1,    // (64)
    const float* __restrict__ W2,    // (64, 64)
    const float* __restrict__ b2,    // (64)
    const float* __restrict__ Wout,  // (64, 3)
    const float* __restrict__ bout,  // (3)
    float* __restrict__ z)           // (SM1, BATCH)
{
    __shared__ float sW1[3 * 64];
    __shared__ float sb1[64];
    __shared__ float sW2[64 * 64];
    __shared__ float sb2[64];
    __shared__ float sWout[64 * 3];
    __shared__ float sbout[3];

    const int tid = threadIdx.x;
    for (int i = tid; i < 3 * 64; i += 256) sW1[i] = W1[i];
    for (int i = tid; i < 64; i += 256) { sb1[i] = b1[i]; sb2[i] = b2[i]; }
    for (int i = tid; i < 64 * 64; i += 256) sW2[i] = W2[i];
    for (int i = tid; i < 64 * 3; i += 256) sWout[i] = Wout[i];
    if (tid < 3) sbout[tid] = bout[tid];
    __syncthreads();

    const int b  = blockIdx.x * 256 + tid;  // 0..2047
    const int sp = blockIdx.y;              // 0..1022 ; s = sp+1

    // 16 contiguous bytes: (t_{s-1}, x_{s-1}, t_s, x_s); only 8B-aligned -> two float2
    const float2* base2 = reinterpret_cast<const float2*>(ys) + ((size_t)b * SFULL + sp);
    const float2 p0 = base2[0];
    const float2 p1 = base2[1];
    const float x0 = p0.y;
    const float t  = p1.x;
    const float xt = p1.y;

    // layer 1: feats = [xt, t, x0]
    float h1[64];
#pragma unroll
    for (int j = 0; j < 64; ++j) {
        float v = sb1[j];
        v = fmaf(xt, sW1[j],        v);
        v = fmaf(t,  sW1[64 + j],   v);
        v = fmaf(x0, sW1[128 + j],  v);
        h1[j] = fmaxf(v, 0.0f);
    }

    // layer 2 fused with output layer
    float c0 = sbout[0], c1 = sbout[1], c2 = sbout[2];
    for (int j = 0; j < 64; j += 4) {
        float a0 = sb2[j], a1 = sb2[j + 1], a2 = sb2[j + 2], a3 = sb2[j + 3];
#pragma unroll
        for (int k = 0; k < 64; ++k) {
            const float4 w = *reinterpret_cast<const float4*>(&sW2[k * 64 + j]);
            const float hv = h1[k];
            a0 = fmaf(hv, w.x, a0);
            a1 = fmaf(hv, w.y, a1);
            a2 = fmaf(hv, w.z, a2);
            a3 = fmaf(hv, w.w, a3);
        }
        a0 = fmaxf(a0, 0.0f); a1 = fmaxf(a1, 0.0f);
        a2 = fmaxf(a2, 0.0f); a3 = fmaxf(a3, 0.0f);
        c0 = fmaf(a0, sWout[(j + 0) * 3 + 0], c0);
        c1 = fmaf(a0, sWout[(j + 0) * 3 + 1], c1);
        c2 = fmaf(a0, sWout[(j + 0) * 3 + 2], c2);
        c0 = fmaf(a1, sWout[(j + 1) * 3 + 0], c0);
        c1 = fmaf(a1, sWout[(j + 1) * 3 + 1], c1);
        c2 = fmaf(a1, sWout[(j + 1) * 3 + 2], c2);
        c0 = fmaf(a2, sWout[(j + 2) * 3 + 0], c0);
        c1 = fmaf(a2, sWout[(j + 2) * 3 + 1], c1);
        c2 = fmaf(a2, sWout[(j + 2) * 3 + 2], c2);
        c0 = fmaf(a3, sWout[(j + 3) * 3 + 0], c0);
        c1 = fmaf(a3, sWout[(j + 3) * 3 + 1], c1);
        c2 = fmaf(a3, sWout[(j + 3) * 3 + 2], c2);
    }

    // Hermite: [1, 2x, 4x^2 - 2]
    const float zv = c0 + c1 * (2.0f * xt) + c2 * (4.0f * xt * xt - 2.0f);
    z[(size_t)sp * BATCH + b] = zv;
}

// ---------------- reduction helpers ----------------
__device__ __forceinline__ float blk_reduce_max(float v) {
    __shared__ float s[4];
#pragma unroll
    for (int off = 32; off >= 1; off >>= 1) v = fmaxf(v, __shfl_xor(v, off));
    if ((threadIdx.x & 63) == 0) s[threadIdx.x >> 6] = v;
    __syncthreads();
    v = fmaxf(fmaxf(s[0], s[1]), fmaxf(s[2], s[3]));
    __syncthreads();
    return v;
}

__device__ __forceinline__ float blk_reduce_sum(float v) {
    __shared__ float s[4];
#pragma unroll
    for (int off = 32; off >= 1; off >>= 1) v += __shfl_xor(v, off);
    if ((threadIdx.x & 63) == 0) s[threadIdx.x >> 6] = v;
    __syncthreads();
    v = (s[0] + s[1]) + (s[2] + s[3]);
    __syncthreads();
    return v;
}

// ---------------- Kernel 2: per-column softmax + logclip sum ----------------
// grid SM1 blocks, 256 threads; column = z[sp*BATCH + 0..2047] (contiguous)
__global__ __launch_bounds__(256) void col_softmax_kernel(
    const float* __restrict__ z, float* __restrict__ colsum)
{
    const int sp = blockIdx.x;
    const int tid = threadIdx.x;
    const float* col = z + (size_t)sp * BATCH;

    float vals[8];
    float m = -3.4e38f;
#pragma unroll
    for (int i = 0; i < 8; ++i) {
        vals[i] = col[tid + 256 * i];
        m = fmaxf(m, vals[i]);
    }
    const float M = blk_reduce_max(m);

    float se = 0.0f;
#pragma unroll
    for (int i = 0; i < 8; ++i) se += __expf(vals[i] - M);
    const float S = blk_reduce_sum(se);
    const float L = __logf(S);

    float acc = 0.0f;
#pragma unroll
    for (int i = 0; i < 8; ++i) acc += fmaxf(vals[i] - M - L, LN_CLAMP);
    const float T = blk_reduce_sum(acc);
    if (tid == 0) colsum[sp] = T;
}

// ---------------- Kernel 3: final scalar ----------------
__global__ __launch_bounds__(256) void final_reduce_kernel(
    const float* __restrict__ colsum, float* __restrict__ out)
{
    const int tid = threadIdx.x;
    float v = 0.0f;
    for (int i = tid; i < SM1; i += 256) v += colsum[i];
    const float T = blk_reduce_sum(v);
    if (tid == 0) out[0] = T / (float)BATCH;
}

extern "C" void kernel_launch(void* const* d_in, const int* in_sizes, int n_in,
                              void* d_out, int out_size, void* d_ws, size_t ws_size,
                              hipStream_t stream) {
    const float* ys   = (const float*)d_in[0];
    const float* W1   = (const float*)d_in[1];
    const float* b1   = (const float*)d_in[2];
    const float* W2   = (const float*)d_in[3];
    const float* b2   = (const float*)d_in[4];
    const float* Wout = (const float*)d_in[5];
    const float* bout = (const float*)d_in[6];
    float* out = (float*)d_out;

    float* z      = (float*)d_ws;                       // SM1*BATCH floats
    float* colsum = z + (size_t)SM1 * BATCH;            // SM1 floats

    dim3 grid1(BATCH / 256, SM1);
    mlp_z_kernel<<<grid1, 256, 0, stream>>>(ys, W1, b1, W2, b2, Wout, bout, z);
    col_softmax_kernel<<<SM1, 256, 0, stream>>>(z, colsum);
    final_reduce_kernel<<<1, 256, 0, stream>>>(colsum, out);
}

// Round 2
// 69.594 us; speedup vs baseline: 4.0450x; 4.0450x over previous
//
#include <hip/hip_runtime.h>
#include <hip/hip_bf16.h>

#define HIDDEN 64
#define BATCH 2048
#define SFULL 1024
#define SM1 1023
#define LN_CLAMP -23.025850929940457f  // ln(1e-10)
#define SP_PER 33                      // 31 * 33 = 1023

typedef __bf16 bf16x8 __attribute__((ext_vector_type(8)));
typedef float  f32x4  __attribute__((ext_vector_type(4)));

// ---------------- Kernel 1: MFMA MLP -> z[sp*BATCH + b] ----------------
// grid (32, 31), block 256 (4 waves). Wave w handles b-tile of 16 rows:
// b0 = (blockIdx.x*4 + w)*16, iterating sp = blockIdx.y*33 .. +32.
// Per iteration the wave computes h2^T = W2^T @ relu(h1)^T via 8 MFMAs:
//   A = W2^T fragments (preloaded), B = h1^T fragments (computed on VALU).
// D layout (verified m89/m91): lane holds D[row=4g+r][col=lane&15]; here
// row = hidden index within mt-tile, col = point. So each lane owns 16
// hidden values of ONE point -> layer3 is a per-lane dot + shfl_xor(16,32).
__global__ __launch_bounds__(256, 1) void mlp_z_kernel(
    const float* __restrict__ ys,    // (B, S, 2)
    const float* __restrict__ W1,    // (3, 64)
    const float* __restrict__ b1,    // (64)
    const float* __restrict__ W2,    // (64, 64) row-major [k][n]
    const float* __restrict__ b2,    // (64)
    const float* __restrict__ Wout,  // (64, 3)
    const float* __restrict__ bout,  // (3)
    float* __restrict__ z)           // (SM1, BATCH)
{
    const int lane = threadIdx.x & 63;
    const int wv   = threadIdx.x >> 6;
    const int col  = lane & 15;      // point within tile / W2 output column
    const int g    = lane >> 4;      // k-group

    const int b   = (blockIdx.x * 4 + wv) * 16 + col;  // this lane's point
    const int sp0 = blockIdx.y * SP_PER;

    // ---- preload per-lane weight slices (loop-invariant) ----
    // k indices owned by this lane: k_i = (i<8 ? 8g+i : 32+8g+(i-8))
    float w1a[16], w1b[16], w1c[16], b1v[16];
#pragma unroll
    for (int i = 0; i < 16; ++i) {
        const int k = (i < 8) ? (8 * g + i) : (32 + 8 * g + (i - 8));
        w1a[i] = W1[k];          // row 0: multiplies xt
        w1b[i] = W1[64 + k];     // row 1: multiplies t
        w1c[i] = W1[128 + k];    // row 2: multiplies x0
        b1v[i] = b1[k];
    }

    // W2^T as MFMA-A fragments: A[mt*16+col][c*32+8g+j] = W2[c*32+8g+j][mt*16+col]
    bf16x8 wf[4][2];
#pragma unroll
    for (int mt = 0; mt < 4; ++mt)
#pragma unroll
        for (int c = 0; c < 2; ++c)
#pragma unroll
            for (int j = 0; j < 8; ++j)
                wf[mt][c][j] = (__bf16)W2[(c * 32 + 8 * g + j) * 64 + mt * 16 + col];

    // epilogue weights: hidden rows owned by this lane are h = mt*16 + 4g + r
    float b2v[16];
    float woutv[16][3];
#pragma unroll
    for (int mt = 0; mt < 4; ++mt)
#pragma unroll
        for (int r = 0; r < 4; ++r) {
            const int h = mt * 16 + 4 * g + r;
            b2v[mt * 4 + r] = b2[h];
            woutv[mt * 4 + r][0] = Wout[h * 3 + 0];
            woutv[mt * 4 + r][1] = Wout[h * 3 + 1];
            woutv[mt * 4 + r][2] = Wout[h * 3 + 2];
        }
    const float bo0 = bout[0], bo1 = bout[1], bo2 = bout[2];

    const f32x4 zero4 = {0.f, 0.f, 0.f, 0.f};

    for (int it = 0; it < SP_PER; ++it) {
        const int sp = sp0 + it;

        // features of point b at step sp: (t_{sp-?}..): pair loads
        const float2* base2 = reinterpret_cast<const float2*>(ys) + ((size_t)b * SFULL + sp);
        const float2 p0 = base2[0];
        const float2 p1 = base2[1];
        const float x0 = p0.y;
        const float t  = p1.x;
        const float xt = p1.y;

        // layer 1 -> B fragments (h1^T): lane supplies h1[point=col][k_i]
        bf16x8 af[2];
#pragma unroll
        for (int half = 0; half < 2; ++half)
#pragma unroll
            for (int j = 0; j < 8; ++j) {
                const int i = half * 8 + j;
                float v = b1v[i];
                v = fmaf(xt, w1a[i], v);
                v = fmaf(t,  w1b[i], v);
                v = fmaf(x0, w1c[i], v);
                v = fmaxf(v, 0.0f);
                af[half][j] = (__bf16)v;
            }

        // layer 2: h2pre^T = W2^T @ h1^T  (8 MFMAs)
        f32x4 acc[4];
#pragma unroll
        for (int mt = 0; mt < 4; ++mt) {
            acc[mt] = __builtin_amdgcn_mfma_f32_16x16x32_bf16(wf[mt][0], af[0], zero4, 0, 0, 0);
            acc[mt] = __builtin_amdgcn_mfma_f32_16x16x32_bf16(wf[mt][1], af[1], acc[mt], 0, 0, 0);
        }

        // layer 3 (per-lane partial dot over its 16 hidden values)
        float c0 = 0.f, c1 = 0.f, c2 = 0.f;
#pragma unroll
        for (int mt = 0; mt < 4; ++mt)
#pragma unroll
            for (int r = 0; r < 4; ++r) {
                const float h2 = fmaxf(acc[mt][r] + b2v[mt * 4 + r], 0.0f);
                c0 = fmaf(h2, woutv[mt * 4 + r][0], c0);
                c1 = fmaf(h2, woutv[mt * 4 + r][1], c1);
                c2 = fmaf(h2, woutv[mt * 4 + r][2], c2);
            }
        // reduce across the 4 k-groups (lanes sharing lane&15)
        c0 += __shfl_xor(c0, 16); c0 += __shfl_xor(c0, 32);
        c1 += __shfl_xor(c1, 16); c1 += __shfl_xor(c1, 32);
        c2 += __shfl_xor(c2, 16); c2 += __shfl_xor(c2, 32);
        c0 += bo0; c1 += bo1; c2 += bo2;

        // Hermite: [1, 2x, 4x^2 - 2]; lane already holds xt for point col
        const float zv = c0 + c1 * (2.0f * xt) + c2 * fmaf(4.0f * xt, xt, -2.0f);
        if (lane < 16) z[(size_t)sp * BATCH + b] = zv;
    }
}

// ---------------- reduction helpers ----------------
__device__ __forceinline__ float blk_reduce_max(float v) {
    __shared__ float s[4];
#pragma unroll
    for (int off = 32; off >= 1; off >>= 1) v = fmaxf(v, __shfl_xor(v, off));
    if ((threadIdx.x & 63) == 0) s[threadIdx.x >> 6] = v;
    __syncthreads();
    v = fmaxf(fmaxf(s[0], s[1]), fmaxf(s[2], s[3]));
    __syncthreads();
    return v;
}

__device__ __forceinline__ float blk_reduce_sum(float v) {
    __shared__ float s[4];
#pragma unroll
    for (int off = 32; off >= 1; off >>= 1) v += __shfl_xor(v, off);
    if ((threadIdx.x & 63) == 0) s[threadIdx.x >> 6] = v;
    __syncthreads();
    v = (s[0] + s[1]) + (s[2] + s[3]);
    __syncthreads();
    return v;
}

// ---------------- Kernel 2: per-column softmax + logclip sum ----------------
__global__ __launch_bounds__(256) void col_softmax_kernel(
    const float* __restrict__ z, float* __restrict__ colsum)
{
    const int sp = blockIdx.x;
    const int tid = threadIdx.x;
    const float* col = z + (size_t)sp * BATCH;

    float vals[8];
    float m = -3.4e38f;
#pragma unroll
    for (int i = 0; i < 8; ++i) {
        vals[i] = col[tid + 256 * i];
        m = fmaxf(m, vals[i]);
    }
    const float M = blk_reduce_max(m);

    float se = 0.0f;
#pragma unroll
    for (int i = 0; i < 8; ++i) se += __expf(vals[i] - M);
    const float S = blk_reduce_sum(se);
    const float L = __logf(S);

    float acc = 0.0f;
#pragma unroll
    for (int i = 0; i < 8; ++i) acc += fmaxf(vals[i] - M - L, LN_CLAMP);
    const float T = blk_reduce_sum(acc);
    if (tid == 0) colsum[sp] = T;
}

// ---------------- Kernel 3: final scalar ----------------
__global__ __launch_bounds__(256) void final_reduce_kernel(
    const float* __restrict__ colsum, float* __restrict__ out)
{
    const int tid = threadIdx.x;
    float v = 0.0f;
    for (int i = tid; i < SM1; i += 256) v += colsum[i];
    const float T = blk_reduce_sum(v);
    if (tid == 0) out[0] = T / (float)BATCH;
}

extern "C" void kernel_launch(void* const* d_in, const int* in_sizes, int n_in,
                              void* d_out, int out_size, void* d_ws, size_t ws_size,
                              hipStream_t stream) {
    const float* ys   = (const float*)d_in[0];
    const float* W1   = (const float*)d_in[1];
    const float* b1   = (const float*)d_in[2];
    const float* W2   = (const float*)d_in[3];
    const float* b2   = (const float*)d_in[4];
    const float* Wout = (const float*)d_in[5];
    const float* bout = (const float*)d_in[6];
    float* out = (float*)d_out;

    float* z      = (float*)d_ws;                       // SM1*BATCH floats
    float* colsum = z + (size_t)SM1 * BATCH;            // SM1 floats

    dim3 grid1(32, 31);  // 32*4 waves * 16 = 2048 b ; 31*33 = 1023 sp
    mlp_z_kernel<<<grid1, 256, 0, stream>>>(ys, W1, b1, W2, b2, Wout, bout, z);
    col_softmax_kernel<<<SM1, 256, 0, stream>>>(z, colsum);
    final_reduce_kernel<<<1, 256, 0, stream>>>(colsum, out);
}

// Round 3
// 57.394 us; speedup vs baseline: 4.9048x; 1.2126x over previous
//
#include <hip/hip_runtime.h>
#include <hip/hip_bf16.h>

#define HIDDEN 64
#define BATCH 2048
#define SFULL 1024
#define SM1 1023
#define LN_CLAMP -23.025850929940457f  // ln(1e-10)
#define SP_PER 32                      // 32 * 32 = 1024 >= 1023

typedef __bf16 bf16x8 __attribute__((ext_vector_type(8)));
typedef float  f32x4  __attribute__((ext_vector_type(4)));

// Row permutation mapping MFMA D-layout rows to MFMA B-layout k-indices.
// For rho = 16*mt + 4*gg + r:  perm(rho) = 32*(mt>>1) + 8*gg + 4*(mt&1) + r.
// A weight matrix whose row rho holds original row perm(rho) produces a D
// output that is, per-lane, exactly the B-fragment of the NEXT mfma.
__device__ __forceinline__ int permrow(int rho) {
    return 32 * ((rho >> 4) >> 1) + 8 * ((rho >> 2) & 3) + 4 * ((rho >> 4) & 1) + (rho & 3);
}

// ---------------- Kernel 1: 3-layer MLP fully on MFMA ----------------
// grid (32, 32), block 256 (4 waves). Wave w: 16 points b = (bx*4+w)*16+col,
// looping sp in [by*32, by*32+32) (sp<1023). Per iteration:
//   MFMA1 (x4): h1pre^perm = permuted-W1^T @ feats^T  (K=32, only k<3 used)
//   relu+cvt  -> B-frag of MFMA2 (pure in-lane index shuffle)
//   MFMA2 (x8): h2pre^perm = permuted-W2^T @ h1^T
//   relu+cvt  -> B-frag of MFMA3
//   MFMA3 (x2): c_n = Wout^T @ h2  (rows 0..2)
// Lanes g=0 hold c0,c1,c2 for their point; Hermite + store. No shuffles.
__global__ __launch_bounds__(256, 2) void mlp_z_kernel(
    const float* __restrict__ ys,    // (B, S, 2)
    const float* __restrict__ W1,    // (3, 64)
    const float* __restrict__ b1,    // (64)
    const float* __restrict__ W2,    // (64, 64) row-major [k][h]
    const float* __restrict__ b2,    // (64)
    const float* __restrict__ Wout,  // (64, 3)
    const float* __restrict__ bout,  // (3)
    float* __restrict__ z)           // (SM1, BATCH)
{
    const int lane = threadIdx.x & 63;
    const int wv   = threadIdx.x >> 6;
    const int col  = lane & 15;      // point index within tile
    const int g    = lane >> 4;      // k-group

    const int b   = (blockIdx.x * 4 + wv) * 16 + col;
    const int sp0 = blockIdx.y * SP_PER;

    // ---- loop-invariant per-lane weight fragments ----
    // MFMA1 A: A1[16mt+col][8g+j] = (8g+j<3) ? W1[8g+j][perm(16mt+col)] : 0
    bf16x8 a1[4];
    // MFMA2 A: A2[16mt+col][32c+8g+j] = W2[32c+8g+j][perm(16mt+col)]
    bf16x8 a2[4][2];
    // MFMA3 A: A3[col][32c+8g+j] = (col<3) ? Wout[32c+8g+j][col] : 0
    bf16x8 a3[2];
#pragma unroll
    for (int mt = 0; mt < 4; ++mt) {
        const int p2 = permrow(16 * mt + col);
#pragma unroll
        for (int j = 0; j < 8; ++j) {
            const int k = 8 * g + j;
            a1[mt][j] = (k < 3) ? (__bf16)W1[k * 64 + p2] : (__bf16)0.0f;
        }
#pragma unroll
        for (int c = 0; c < 2; ++c)
#pragma unroll
            for (int j = 0; j < 8; ++j)
                a2[mt][c][j] = (__bf16)W2[(32 * c + 8 * g + j) * 64 + p2];
    }
#pragma unroll
    for (int c = 0; c < 2; ++c)
#pragma unroll
        for (int j = 0; j < 8; ++j)
            a3[c][j] = (col < 3) ? (__bf16)Wout[(32 * c + 8 * g + j) * 3 + col] : (__bf16)0.0f;

    // bias C-inits (D-layout rows: 16mt + 4g + r)
    f32x4 c1init[4], c2init[4];
#pragma unroll
    for (int mt = 0; mt < 4; ++mt)
#pragma unroll
        for (int r = 0; r < 4; ++r) {
            const int pd = permrow(16 * mt + 4 * g + r);
            c1init[mt][r] = b1[pd];
            c2init[mt][r] = b2[pd];
        }
    f32x4 c3init = {0.f, 0.f, 0.f, 0.f};
    if (g == 0) { c3init[0] = bout[0]; c3init[1] = bout[1]; c3init[2] = bout[2]; }

    const float2* base2 = reinterpret_cast<const float2*>(ys) + ((size_t)b * SFULL + sp0);
    float2 p = base2[0];  // (t_{sp0}, x_{sp0})

    for (int it = 0; it < SP_PER; ++it) {
        const int sp = sp0 + it;
        if (sp >= SM1) break;  // uniform: only last block's last iter

        const float2 q = base2[it + 1];
        const float x0 = p.y;
        const float t  = q.x;
        const float xt = q.y;
        p = q;

        // feats B-frag: B0[8g+j][col] = (k==0:xt, 1:t, 2:x0, else 0)
        bf16x8 f0 = {};
        if (g == 0) {
            f0[0] = (__bf16)xt; f0[1] = (__bf16)t; f0[2] = (__bf16)x0;
        }

        // layer 1
        f32x4 acc1[4];
#pragma unroll
        for (int mt = 0; mt < 4; ++mt)
            acc1[mt] = __builtin_amdgcn_mfma_f32_16x16x32_bf16(a1[mt], f0, c1init[mt], 0, 0, 0);

        // relu + cvt -> B-frag of layer 2 (in-lane only)
        bf16x8 hf[2];
#pragma unroll
        for (int c = 0; c < 2; ++c)
#pragma unroll
            for (int j = 0; j < 8; ++j)
                hf[c][j] = (__bf16)fmaxf(acc1[2 * c + (j >> 2)][j & 3], 0.0f);

        // layer 2
        f32x4 acc2[4];
#pragma unroll
        for (int mt = 0; mt < 4; ++mt) {
            acc2[mt] = __builtin_amdgcn_mfma_f32_16x16x32_bf16(a2[mt][0], hf[0], c2init[mt], 0, 0, 0);
            acc2[mt] = __builtin_amdgcn_mfma_f32_16x16x32_bf16(a2[mt][1], hf[1], acc2[mt], 0, 0, 0);
        }

        // relu + cvt -> B-frag of layer 3
        bf16x8 h2f[2];
#pragma unroll
        for (int c = 0; c < 2; ++c)
#pragma unroll
            for (int j = 0; j < 8; ++j)
                h2f[c][j] = (__bf16)fmaxf(acc2[2 * c + (j >> 2)][j & 3], 0.0f);

        // layer 3: c_n rows 0..2 (lane g==0 holds them for its point)
        f32x4 acc3;
        acc3 = __builtin_amdgcn_mfma_f32_16x16x32_bf16(a3[0], h2f[0], c3init, 0, 0, 0);
        acc3 = __builtin_amdgcn_mfma_f32_16x16x32_bf16(a3[1], h2f[1], acc3, 0, 0, 0);

        // Hermite: z = c0 + c1*(2x) + c2*(4x^2-2)
        const float u  = xt + xt;
        const float v  = fmaf(4.0f * xt, xt, -2.0f);
        const float zv = fmaf(acc3[2], v, fmaf(acc3[1], u, acc3[0]));
        if (lane < 16) z[(size_t)sp * BATCH + b] = zv;
    }
}

// ---------------- reduction helpers ----------------
__device__ __forceinline__ float blk_reduce_max(float v) {
    __shared__ float s[4];
#pragma unroll
    for (int off = 32; off >= 1; off >>= 1) v = fmaxf(v, __shfl_xor(v, off));
    if ((threadIdx.x & 63) == 0) s[threadIdx.x >> 6] = v;
    __syncthreads();
    v = fmaxf(fmaxf(s[0], s[1]), fmaxf(s[2], s[3]));
    __syncthreads();
    return v;
}

__device__ __forceinline__ float blk_reduce_sum(float v) {
    __shared__ float s[4];
#pragma unroll
    for (int off = 32; off >= 1; off >>= 1) v += __shfl_xor(v, off);
    if ((threadIdx.x & 63) == 0) s[threadIdx.x >> 6] = v;
    __syncthreads();
    v = (s[0] + s[1]) + (s[2] + s[3]);
    __syncthreads();
    return v;
}

// ---------------- Kernel 2: per-column softmax + logclip sum ----------------
__global__ __launch_bounds__(256) void col_softmax_kernel(
    const float* __restrict__ z, float* __restrict__ colsum)
{
    const int sp = blockIdx.x;
    const int tid = threadIdx.x;
    const float* col = z + (size_t)sp * BATCH;

    float vals[8];
    float m = -3.4e38f;
#pragma unroll
    for (int i = 0; i < 8; ++i) {
        vals[i] = col[tid + 256 * i];
        m = fmaxf(m, vals[i]);
    }
    const float M = blk_reduce_max(m);

    float se = 0.0f;
#pragma unroll
    for (int i = 0; i < 8; ++i) se += __expf(vals[i] - M);
    const float S = blk_reduce_sum(se);
    const float L = __logf(S);

    float acc = 0.0f;
#pragma unroll
    for (int i = 0; i < 8; ++i) acc += fmaxf(vals[i] - M - L, LN_CLAMP);
    const float T = blk_reduce_sum(acc);
    if (tid == 0) colsum[sp] = T;
}

// ---------------- Kernel 3: final scalar ----------------
__global__ __launch_bounds__(256) void final_reduce_kernel(
    const float* __restrict__ colsum, float* __restrict__ out)
{
    const int tid = threadIdx.x;
    float v = 0.0f;
    for (int i = tid; i < SM1; i += 256) v += colsum[i];
    const float T = blk_reduce_sum(v);
    if (tid == 0) out[0] = T / (float)BATCH;
}

extern "C" void kernel_launch(void* const* d_in, const int* in_sizes, int n_in,
                              void* d_out, int out_size, void* d_ws, size_t ws_size,
                              hipStream_t stream) {
    const float* ys   = (const float*)d_in[0];
    const float* W1   = (const float*)d_in[1];
    const float* b1   = (const float*)d_in[2];
    const float* W2   = (const float*)d_in[3];
    const float* b2   = (const float*)d_in[4];
    const float* Wout = (const float*)d_in[5];
    const float* bout = (const float*)d_in[6];
    float* out = (float*)d_out;

    float* z      = (float*)d_ws;                       // SM1*BATCH floats
    float* colsum = z + (size_t)SM1 * BATCH;            // SM1 floats

    dim3 grid1(32, 32);  // 32*4 waves * 16 = 2048 b ; 32*32 = 1024 >= 1023 sp
    mlp_z_kernel<<<grid1, 256, 0, stream>>>(ys, W1, b1, W2, b2, Wout, bout, z);
    col_softmax_kernel<<<SM1, 256, 0, stream>>>(z, colsum);
    final_reduce_kernel<<<1, 256, 0, stream>>>(colsum, out);
}

// Round 4
// 49.128 us; speedup vs baseline: 5.7300x; 1.1683x over previous
//
#include <hip/hip_runtime.h>
#include <hip/hip_bf16.h>

#define HIDDEN 64
#define BATCH 2048
#define SFULL 1024
#define SM1 1023
#define LN_CLAMP -23.025850929940457f  // ln(1e-10)
#define PAIRS 16                       // 32 sp per block (grid.y = 32)

typedef __bf16 bf16x8 __attribute__((ext_vector_type(8)));
typedef float  f32x4  __attribute__((ext_vector_type(4)));

// Row permutation mapping MFMA D-layout rows to MFMA B-layout k-indices.
// For rho = 16*mt + 4*gg + r:  perm(rho) = 32*(mt>>1) + 8*gg + 4*(mt&1) + r.
// Hardware-verified in R2 (absmax 0.0).
__device__ __forceinline__ int permrow(int rho) {
    return 32 * ((rho >> 4) >> 1) + 8 * ((rho >> 2) & 3) + 4 * ((rho >> 4) & 1) + (rho & 3);
}

// ---------------- Kernel 1: 3-layer MLP fully on MFMA, 2 sp-chains/iter ----
// grid (32, 32), block 256 (4 waves). Wave w: 16 points b = (bx*4+w)*16+col.
// Each loop iteration runs TWO independent chains (sp, sp+1) sharing loads:
//   MFMA1 x4 : h1pre^perm = permW1^T @ [xt,t,x0,1]^T (bias folded into k=3)
//   relu+cvt -> B-frag (in-lane)  -> MFMA2 x8 -> relu+cvt -> MFMA3 x2
// Lanes g=0 hold c0,c1,c2; Hermite + store. No shuffles, no LDS, no branches
// in the chain.
__global__ __launch_bounds__(256, 3) void mlp_z_kernel(
    const float* __restrict__ ys,    // (B, S, 2)
    const float* __restrict__ W1,    // (3, 64)
    const float* __restrict__ b1,    // (64)
    const float* __restrict__ W2,    // (64, 64) row-major [k][h]
    const float* __restrict__ b2,    // (64)
    const float* __restrict__ Wout,  // (64, 3)
    const float* __restrict__ bout,  // (3)
    float* __restrict__ z)           // (SM1, BATCH)
{
    const int lane = threadIdx.x & 63;
    const int wv   = threadIdx.x >> 6;
    const int col  = lane & 15;      // point index within tile
    const int g    = lane >> 4;      // k-group

    const int b   = (blockIdx.x * 4 + wv) * 16 + col;
    const int sp0 = blockIdx.y * (2 * PAIRS);
    const int omax = (SFULL - 1) - sp0;  // last valid float2 offset from base2

    // ---- loop-invariant per-lane weight fragments ----
    // MFMA1 A: k<3 -> W1[k][perm], k==3 -> b1[perm] (bias row), else 0
    bf16x8 a1[4];
    // MFMA2 A: A2[16mt+col][32c+8g+j] = W2[32c+8g+j][perm(16mt+col)]
    bf16x8 a2[4][2];
    // MFMA3 A: A3[col][32c+8g+j] = (col<3) ? Wout[32c+8g+j][col] : 0
    bf16x8 a3[2];
#pragma unroll
    for (int mt = 0; mt < 4; ++mt) {
        const int p2 = permrow(16 * mt + col);
#pragma unroll
        for (int j = 0; j < 8; ++j) {
            const int k = 8 * g + j;
            a1[mt][j] = (k < 3) ? (__bf16)W1[k * 64 + p2]
                      : (k == 3) ? (__bf16)b1[p2] : (__bf16)0.0f;
        }
#pragma unroll
        for (int c = 0; c < 2; ++c)
#pragma unroll
            for (int j = 0; j < 8; ++j)
                a2[mt][c][j] = (__bf16)W2[(32 * c + 8 * g + j) * 64 + p2];
    }
#pragma unroll
    for (int c = 0; c < 2; ++c)
#pragma unroll
        for (int j = 0; j < 8; ++j)
            a3[c][j] = (col < 3) ? (__bf16)Wout[(32 * c + 8 * g + j) * 3 + col] : (__bf16)0.0f;

    // layer-2 bias C-init (D-layout rows: perm(16mt + 4g + r))
    f32x4 c2init[4];
#pragma unroll
    for (int mt = 0; mt < 4; ++mt)
#pragma unroll
        for (int r = 0; r < 4; ++r)
            c2init[mt][r] = b2[permrow(16 * mt + 4 * g + r)];
    f32x4 c3init = {0.f, 0.f, 0.f, 0.f};
    if (g == 0) { c3init[0] = bout[0]; c3init[1] = bout[1]; c3init[2] = bout[2]; }

    const f32x4 zero4 = {0.f, 0.f, 0.f, 0.f};

    const float2* base2 = reinterpret_cast<const float2*>(ys) + ((size_t)b * SFULL + sp0);
    float* zb = z + (size_t)sp0 * BATCH + b;

    float2 qa = base2[0];
    float2 qb = base2[1];
    float2 qc = base2[2];

    for (int it = 0; it < PAIRS; ++it) {
        // prefetch next pair's inputs (offsets clamped -> always in-bounds)
        const int o1n = min(2 * it + 3, omax);
        const int o2n = min(2 * it + 4, omax);
        const float2 nb = base2[o1n];
        const float2 nc = base2[o2n];

        // chain A: sp = sp0+2it ; chain B: sp+1
        const float x0a = qa.y, ta = qb.x, xta = qb.y;
        const float x0b = qb.y, tb = qc.x, xtb = qc.y;

        // branchless B0 frag: A1 cols k>=4 are zero, so every lane can carry
        // the same pattern; only g==0 lanes' k=0..3 values matter.
        bf16x8 f0a, f0b;
        f0a[0] = (__bf16)xta; f0a[1] = (__bf16)ta;
        f0a[2] = (__bf16)x0a; f0a[3] = (__bf16)1.0f;
        f0a[4] = f0a[0]; f0a[5] = f0a[1]; f0a[6] = f0a[2]; f0a[7] = f0a[3];
        f0b[0] = (__bf16)xtb; f0b[1] = (__bf16)tb;
        f0b[2] = (__bf16)x0b; f0b[3] = (__bf16)1.0f;
        f0b[4] = f0b[0]; f0b[5] = f0b[1]; f0b[6] = f0b[2]; f0b[7] = f0b[3];

        // ---- layer 1 (bias folded in) ----
        f32x4 acc1a[4], acc1b[4];
#pragma unroll
        for (int mt = 0; mt < 4; ++mt) {
            acc1a[mt] = __builtin_amdgcn_mfma_f32_16x16x32_bf16(a1[mt], f0a, zero4, 0, 0, 0);
            acc1b[mt] = __builtin_amdgcn_mfma_f32_16x16x32_bf16(a1[mt], f0b, zero4, 0, 0, 0);
        }

        // relu + cvt -> B-frags (in-lane index shuffle only)
        bf16x8 hfa[2], hfb[2];
#pragma unroll
        for (int c = 0; c < 2; ++c)
#pragma unroll
            for (int j = 0; j < 8; ++j) {
                hfa[c][j] = (__bf16)fmaxf(acc1a[2 * c + (j >> 2)][j & 3], 0.0f);
                hfb[c][j] = (__bf16)fmaxf(acc1b[2 * c + (j >> 2)][j & 3], 0.0f);
            }

        // ---- layer 2 ----
        f32x4 acc2a[4], acc2b[4];
#pragma unroll
        for (int mt = 0; mt < 4; ++mt) {
            acc2a[mt] = __builtin_amdgcn_mfma_f32_16x16x32_bf16(a2[mt][0], hfa[0], c2init[mt], 0, 0, 0);
            acc2b[mt] = __builtin_amdgcn_mfma_f32_16x16x32_bf16(a2[mt][0], hfb[0], c2init[mt], 0, 0, 0);
        }
#pragma unroll
        for (int mt = 0; mt < 4; ++mt) {
            acc2a[mt] = __builtin_amdgcn_mfma_f32_16x16x32_bf16(a2[mt][1], hfa[1], acc2a[mt], 0, 0, 0);
            acc2b[mt] = __builtin_amdgcn_mfma_f32_16x16x32_bf16(a2[mt][1], hfb[1], acc2b[mt], 0, 0, 0);
        }

        bf16x8 h2fa[2], h2fb[2];
#pragma unroll
        for (int c = 0; c < 2; ++c)
#pragma unroll
            for (int j = 0; j < 8; ++j) {
                h2fa[c][j] = (__bf16)fmaxf(acc2a[2 * c + (j >> 2)][j & 3], 0.0f);
                h2fb[c][j] = (__bf16)fmaxf(acc2b[2 * c + (j >> 2)][j & 3], 0.0f);
            }

        // ---- layer 3 ----
        f32x4 acc3a, acc3b;
        acc3a = __builtin_amdgcn_mfma_f32_16x16x32_bf16(a3[0], h2fa[0], c3init, 0, 0, 0);
        acc3b = __builtin_amdgcn_mfma_f32_16x16x32_bf16(a3[0], h2fb[0], c3init, 0, 0, 0);
        acc3a = __builtin_amdgcn_mfma_f32_16x16x32_bf16(a3[1], h2fa[1], acc3a, 0, 0, 0);
        acc3b = __builtin_amdgcn_mfma_f32_16x16x32_bf16(a3[1], h2fb[1], acc3b, 0, 0, 0);

        // Hermite: z = c0 + c1*(2x) + c2*(4x^2-2)
        const float zva = fmaf(acc3a[2], fmaf(4.0f * xta, xta, -2.0f),
                          fmaf(acc3a[1], xta + xta, acc3a[0]));
        const float zvb = fmaf(acc3b[2], fmaf(4.0f * xtb, xtb, -2.0f),
                          fmaf(acc3b[1], xtb + xtb, acc3b[0]));

        if (lane < 16) {
            zb[(size_t)(2 * it) * BATCH] = zva;
            if (sp0 + 2 * it + 1 < SM1)  // only skips (by=31, it=15) second sp
                zb[(size_t)(2 * it + 1) * BATCH] = zvb;
        }

        qa = qc; qb = nb; qc = nc;
    }
}

// ---------------- reduction helpers ----------------
__device__ __forceinline__ float blk_reduce_max(float v) {
    __shared__ float s[4];
#pragma unroll
    for (int off = 32; off >= 1; off >>= 1) v = fmaxf(v, __shfl_xor(v, off));
    if ((threadIdx.x & 63) == 0) s[threadIdx.x >> 6] = v;
    __syncthreads();
    v = fmaxf(fmaxf(s[0], s[1]), fmaxf(s[2], s[3]));
    __syncthreads();
    return v;
}

__device__ __forceinline__ float blk_reduce_sum(float v) {
    __shared__ float s[4];
#pragma unroll
    for (int off = 32; off >= 1; off >>= 1) v += __shfl_xor(v, off);
    if ((threadIdx.x & 63) == 0) s[threadIdx.x >> 6] = v;
    __syncthreads();
    v = (s[0] + s[1]) + (s[2] + s[3]);
    __syncthreads();
    return v;
}

// ---------------- Kernel 2: per-column softmax + logclip sum ----------------
__global__ __launch_bounds__(256) void col_softmax_kernel(
    const float* __restrict__ z, float* __restrict__ colsum)
{
    const int sp = blockIdx.x;
    const int tid = threadIdx.x;
    const float* col = z + (size_t)sp * BATCH;

    float vals[8];
    float m = -3.4e38f;
#pragma unroll
    for (int i = 0; i < 8; ++i) {
        vals[i] = col[tid + 256 * i];
        m = fmaxf(m, vals[i]);
    }
    const float M = blk_reduce_max(m);

    float se = 0.0f;
#pragma unroll
    for (int i = 0; i < 8; ++i) se += __expf(vals[i] - M);
    const float S = blk_reduce_sum(se);
    const float L = __logf(S);

    float acc = 0.0f;
#pragma unroll
    for (int i = 0; i < 8; ++i) acc += fmaxf(vals[i] - M - L, LN_CLAMP);
    const float T = blk_reduce_sum(acc);
    if (tid == 0) colsum[sp] = T;
}

// ---------------- Kernel 3: final scalar ----------------
__global__ __launch_bounds__(256) void final_reduce_kernel(
    const float* __restrict__ colsum, float* __restrict__ out)
{
    const int tid = threadIdx.x;
    float v = 0.0f;
    for (int i = tid; i < SM1; i += 256) v += colsum[i];
    const float T = blk_reduce_sum(v);
    if (tid == 0) out[0] = T / (float)BATCH;
}

extern "C" void kernel_launch(void* const* d_in, const int* in_sizes, int n_in,
                              void* d_out, int out_size, void* d_ws, size_t ws_size,
                              hipStream_t stream) {
    const float* ys   = (const float*)d_in[0];
    const float* W1   = (const float*)d_in[1];
    const float* b1   = (const float*)d_in[2];
    const float* W2   = (const float*)d_in[3];
    const float* b2   = (const float*)d_in[4];
    const float* Wout = (const float*)d_in[5];
    const float* bout = (const float*)d_in[6];
    float* out = (float*)d_out;

    float* z      = (float*)d_ws;                       // SM1*BATCH floats
    float* colsum = z + (size_t)SM1 * BATCH;            // SM1 floats

    dim3 grid1(32, 32);  // 32*4 waves * 16 pts = 2048 b ; 32*32 = 1024 sp slots
    mlp_z_kernel<<<grid1, 256, 0, stream>>>(ys, W1, b1, W2, b2, Wout, bout, z);
    col_softmax_kernel<<<SM1, 256, 0, stream>>>(z, colsum);
    final_reduce_kernel<<<1, 256, 0, stream>>>(colsum, out);
}